// Round 18
// baseline (74.174 us; speedup 1.0000x reference)
//
#include <hip/hip_runtime.h>
#include <cstdint>
#include <cstddef>

#define NFEAT 3872
#define NPAIR 120
#define NB    32768
#define ZD    128
#define NPOLY 1000
#define NSEL  512
#define SOFT  1e-3f

#define STHREADS 512   // stats block size
#define NZSLOT   1856  // wave-uniform zn slot count (64-aligned op segments, fused)
#define ZCHUNK   4     // slots tid + k*512
#define SB       64    // superbatch rows (whole block share staged at once)
#define RO       8     // rows per batch, out
#define VCHUNK   32    // var reduction stage-1 chunk count (8 starved var1; r10 -3.2us)
#define RSLICE   32    // rank stage-1 slices (NFEAT/RSLICE = 121)
#define RGSZ     121   // NFEAT / RSLICE
#define MAXT     1280  // max padded tasks (9 ops: 512 + 9*63 = 1079)
#define TPT      5     // max tasks per thread in out (MAXT/256)

// ---------------------------------------------------------------------------
// Feature id layout (reference order):
//   [0,128) zn | [128,1808) 14 dist blocks x 120 pairs | [1808,1936) zn^2
//   [1936,2064) sin | [2064,2192) cos | [2192,2320) log|zn|+1e-3
//   [2320,2448) exp(clip) | [2448,2464) p_sq | [2464,2912) intra | [2912,3872) inter
// stats zn plan word: op(3b) | a0(7b)<<3 | a1(7b)<<10 | fid(12b)<<17 (4095=none)
// out task word: op(5b) | a0(7b)<<5 | a1(7b)<<12 | dst(9b)<<19
// OUT op set (merged, 9 real ops; r9-proven). r12: direct scatter regressed.
// r13: out not occupancy-limited; rpb_out=32. r15/r16: merged-role stats
// refuted. r18: tasks are batch-invariant -> preloaded to registers once
// (ntask 64-aligned => per-thread count wave-uniform; static k-indexing).
// ---------------------------------------------------------------------------

// Newton-refined reciprocal: used only in cold/one-time paths.
__device__ __forceinline__ float frcp(float x) {
  float r = __builtin_amdgcn_rcpf(x);
  float e = fmaf(-x, r, 1.0f);
  return fmaf(r, e, r);
}
// Raw HW reciprocal (~1e-6 rel err) for hot loops: below the f32
// block-accumulation noise floor (~1e-5) that already passes.
__device__ __forceinline__ float frcpr(float x) {
  return __builtin_amdgcn_rcpf(x);
}

#define FSIN(x) __sinf(x)
#define FCOS(x) __cosf(x)
#define FLOG(x) __logf(x)
#define FEXP(x) __expf(x)

// Parallel table init.
__device__ __forceinline__ void init_tables_par(int tid, unsigned char* IUs, unsigned char* JUs,
                                                unsigned char* IIs, unsigned char* JJs) {
  if (tid < NPAIR) {
    int i = 0, rem = tid;
    while (rem >= 15 - i) { rem -= 15 - i; ++i; }
    IUs[tid] = (unsigned char)i; JUs[tid] = (unsigned char)(i + 1 + rem);
  }
  if (tid < 28) {
    int i = 0, rem = tid;
    while (rem >= 7 - i) { rem -= 7 - i; ++i; }
    IIs[tid] = (unsigned char)i; JJs[tid] = (unsigned char)(i + 1 + rem);
  }
}

// Out-kernel plan packing with the merged 9-op set (r9-proven).
__device__ __forceinline__ int pack_plan(int f, const unsigned char* IUs, const unsigned char* JUs,
                                         const unsigned char* IIs, const unsigned char* JJs) {
  int op = 31, a0 = 0, a1 = 0;
  if (f < 128) { op = 0; a0 = f; }
  else if (f < 1808) {
    int t = f - 128; int b = t / 120; int p = t - b * 120; a0 = p;
    if (b == 0) op = 1;
    else if (b == 11) { op = 3; a1 = 0; }
    else if (b == 12) op = 4;
    else if (b == 13) { op = 5; a1 = 0; }
    else {
      // b in 1..10 -> exponent n: 1, then POWERS = 2,3,4,5,6,8,10,12,14
      const int P[10] = {1, 2, 3, 4, 5, 6, 8, 10, 12, 14};
      op = 2; a1 = P[b - 1];
    }
  }
  else if (f < 1936) { op = 8; a0 = f - 1808; a1 = a0; }   // zn^2 == zn*zn
  else if (f < 2064) { op = 6; a0 = f - 1936; a1 = 0; }    // sin
  else if (f < 2192) { op = 6; a0 = f - 2064; a1 = 1; }    // cos
  else if (f < 2320) { op = 5; a0 = f - 2192; a1 = 1; }    // log|zn|+1e-3
  else if (f < 2448) { op = 3; a0 = f - 2320; a1 = 1; }    // exp(clip(zn))
  else if (f < 2464) { op = 7; a0 = (f - 2448) * 8; }
  else if (f < 2912) { int t = f - 2464; int n = t / 28; int qq = t - n * 28;
                       op = 8; a0 = n * 8 + IIs[qq]; a1 = n * 8 + JJs[qq]; }
  else if (f < NFEAT) { int t = f - 2912; int p = t >> 3; int kk = t & 7;
                        op = 8; a0 = IUs[p] * 8 + kk; a1 = JUs[p] * 8 + kk; }
  return op | (a0 << 5) | (a1 << 12);
}

// ---------------------------------------------------------------------------
// Wave-uniform slot layout, stats zn role (unchanged from r6).
// ---------------------------------------------------------------------------
__device__ __forceinline__ int decode_zslot(int s, const unsigned char* IUs, const unsigned char* JUs,
                                            const unsigned char* IIs, const unsigned char* JJs) {
  int op = 0, a0 = 0, a1 = 0, fid = 4095;
  if (s < 128) { op = 1; a0 = s; fid = s; }
  else if (s < 256) { op = 2; a0 = s - 128; fid = 1936 + (s - 128); }
  else if (s < 384) { op = 3; a0 = s - 256; fid = 2192 + (s - 256); }
  else if (s < 448) {
    int q = s - 384;
    op = 4;
    a0 = (q < 16) ? q * 8 : 0;       // pad lanes compute garbage, never stored
    if (q < 16) fid = 2448 + q;
  } else if (s < 896) {
    int t = s - 448;
    int n = t / 28, qq = t - n * 28;
    op = 5; a0 = n * 8 + IIs[qq]; a1 = n * 8 + JJs[qq]; fid = 2464 + t;
  } else if (s < NZSLOT) {
    int t = s - 896;
    int p = t >> 3, kk = t & 7;
    op = 5; a0 = IUs[p] * 8 + kk; a1 = JUs[p] * 8 + kk; fid = 2912 + t;
  }
  return op | (a0 << 3) | (a1 << 10) | (fid << 17);
}

// ---------------------------------------------------------------------------
// Pass 1 (merged, parity-interleaved roles; even = zn, odd = dist).
// Superbatch: stage all 64 rows once; 2 barriers in the compute path.
// f32 accumulation + f32 partial stores (promoted to f64 in var1).
// Dist reduction tail batched: all 14 features per phase -> 4 barriers.
// ---------------------------------------------------------------------------
__global__ __launch_bounds__(STHREADS) void stats_kernel(const float* __restrict__ z,
                                                         const float* __restrict__ zmean,
                                                         const float* __restrict__ zstd,
                                                         float* __restrict__ psum,
                                                         float* __restrict__ psumsq,
                                                         int rows_per_block) {
  __shared__ __align__(16) union {
    struct { float zm[ZD]; float rz[ZD]; float zn[SB * ZD]; } zns;       // ~33 KB
    struct { float zc[SB * 32]; float red[4][14][NPAIR]; } ds;           // ~34.3 KB
  } sh;
  __shared__ unsigned char IUs[NPAIR], JUs[NPAIR], IIs[28], JJs[28];
  int tid = threadIdx.x;
  init_tables_par(tid, IUs, JUs, IIs, JJs);
  int bx = blockIdx.x;
  int b = bx >> 1;
  int row0 = b * rows_per_block;
  int row1 = min(row0 + rows_per_block, NB);

  if ((bx & 1) == 0) {
    // ---------------- zn role ----------------
    if (tid < ZD) { sh.zns.zm[tid] = zmean[tid]; sh.zns.rz[tid] = frcp(zstd[tid]); }
    __syncthreads();

    int plan[ZCHUNK];
#pragma unroll
    for (int k = 0; k < ZCHUNK; ++k)
      plan[k] = decode_zslot(tid + k * STHREADS, IUs, JUs, IIs, JJs);

    float s[ZCHUNK], q[ZCHUNK], s2 = 0.0f, q2 = 0.0f;
#pragma unroll
    for (int k = 0; k < ZCHUNK; ++k) { s[k] = 0.0f; q[k] = 0.0f; }

#define ROWLOOP _Pragma("unroll 8") for (int rr = 0; rr < SB; ++rr)
#define ACC  { sk += v; qk = fmaf(v, v, qk); }
#define ACC2 { sk2 += v2; qk2 = fmaf(v2, v2, qk2); }

    for (int r0 = row0; r0 < row1; r0 += SB) {
      const float4* z4 = (const float4*)(z + (size_t)r0 * ZD);
#pragma unroll
      for (int u = 0; u < SB * ZD / 4 / STHREADS; ++u) {
        int t = u * STHREADS + tid;
        float4 v = z4[t];
        int c4 = t & 31;
        v.x = fminf(fmaxf(v.x, -1e6f), 1e6f);
        v.y = fminf(fmaxf(v.y, -1e6f), 1e6f);
        v.z = fminf(fmaxf(v.z, -1e6f), 1e6f);
        v.w = fminf(fmaxf(v.w, -1e6f), 1e6f);
        float4 m4 = ((const float4*)sh.zns.zm)[c4];
        float4 r4 = ((const float4*)sh.zns.rz)[c4];
        float4 o;
        o.x = (v.x - m4.x) * r4.x;
        o.y = (v.y - m4.y) * r4.y;
        o.z = (v.z - m4.z) * r4.z;
        o.w = (v.w - m4.w) * r4.w;
        ((float4*)sh.zns.zn)[t] = o;
      }
      __syncthreads();
      const float* znS = sh.zns.zn;
      // ---- chunk 0: mixed ops, wave-uniform switch ----
      {
        int pk = plan[0];
        int a0 = (pk >> 3) & 127, a1 = (pk >> 10) & 127;
        int wop = __builtin_amdgcn_readfirstlane(pk & 7);
        float sk = 0.0f, qk = 0.0f, sk2 = 0.0f, qk2 = 0.0f;
        switch (wop) {
          case 1: ROWLOOP { float v = znS[rr * ZD + a0];
                            float v2 = v * v; ACC ACC2 } break;
          case 2: ROWLOOP { float x = znS[rr * ZD + a0];
                            float v, v2; __sincosf(x, &v, &v2); ACC ACC2 } break;
          case 3: ROWLOOP { float x = znS[rr * ZD + a0];
                            float v = FLOG(fabsf(x) + 0.001f);
                            float xc = fminf(fmaxf(x, -10.0f), 2.0f);
                            float v2 = FEXP(xc); ACC ACC2 } break;
          case 4: ROWLOOP { const float* zr = znS + rr * ZD + a0;
                            float x4 = zr[4]; float x5 = zr[5]; float x6 = zr[6]; float x7 = zr[7];
                            float v = x4 * x4 + x5 * x5 + x6 * x6 + x7 * x7; ACC } break;
          case 5: ROWLOOP { const float* zr = znS + rr * ZD; float v = zr[a0] * zr[a1]; ACC } break;
          default: break;
        }
        s[0] += sk; q[0] += qk;
        if (wop >= 1 && wop <= 3) { s2 += sk2; q2 += qk2; }
      }
      // ---- chunks 1..3: statically all-op5 (chunk 3 idle past 1856) ----
#pragma unroll
      for (int k = 1; k < ZCHUNK; ++k) {
        int pk = plan[k];
        int a0 = (pk >> 3) & 127, a1 = (pk >> 10) & 127;
        int act = __builtin_amdgcn_readfirstlane((int)(((pk >> 17) & 4095) != 4095));
        if (act) {
          float sk = 0.0f, qk = 0.0f;
          ROWLOOP { const float* zr = znS + rr * ZD; float v = zr[a0] * zr[a1]; ACC }
          s[k] += sk; q[k] += qk;
        }
      }
      __syncthreads();
    }
#undef ROWLOOP
#undef ACC
#undef ACC2

#pragma unroll
    for (int k = 0; k < ZCHUNK; ++k) {
      int fid = (plan[k] >> 17) & 4095;
      int opk = plan[k] & 7;
      if (fid != 4095) {
        psum[(size_t)b * NFEAT + fid] = s[k];
        psumsq[(size_t)b * NFEAT + fid] = q[k];
        if (k == 0 && opk >= 1 && opk <= 3) {
          int fid2 = fid + ((opk == 1) ? 1808 : 128);
          psum[(size_t)b * NFEAT + fid2] = s2;
          psumsq[(size_t)b * NFEAT + fid2] = q2;
        }
      }
    }
  } else {
    // ---------------- dist role ----------------
    __syncthreads();    // tables visible
    int p  = tid & 127;
    int rg = tid >> 7;                         // 0..3
    int ni = (p < NPAIR) ? IUs[p] : 0;
    int nj = (p < NPAIR) ? JUs[p] : 0;

    float sF[14], qF[14];
#pragma unroll
    for (int bb = 0; bb < 14; ++bb) { sF[bb] = 0.0f; qF[bb] = 0.0f; }

    for (int r0 = row0; r0 < row1; r0 += SB) {
#pragma unroll
      for (int u = 0; u < SB * 32 / STHREADS; ++u) {
        int t = u * STHREADS + tid;
        int rr = t >> 5, c = t & 31;
        int col = ((c >> 1) << 3) + (c & 1);
        float v = z[(size_t)(r0 + rr) * ZD + col];
        sh.ds.zc[t] = fminf(fmaxf(v, -1e6f), 1e6f);
      }
      __syncthreads();
      if (p < NPAIR) {
        for (int rr = rg; rr < SB; rr += 4) {
          const float* zc = sh.ds.zc + rr * 32;
          float dx = zc[ni * 2 + 0] - zc[nj * 2 + 0];
          float dy = zc[ni * 2 + 1] - zc[nj * 2 + 1];
          dx = fmaf(-10.0f, rintf(dx * 0.1f), dx);
          dy = fmaf(-10.0f, rintf(dy * 0.1f), dy);
          float d = sqrtf(dx * dx + dy * dy) + 1e-6f;
          float e = FEXP(-d);
          float d2 = d * d,   d3 = d2 * d,  d4 = d2 * d2, d5 = d4 * d, d6 = d4 * d2;
          float d8 = d4 * d4, d10 = d8 * d2, d12 = d8 * d4, d14 = d12 * d2;
          float r1 = frcpr(d + SOFT);
          float v[14];
          v[0]  = d;
          v[1]  = r1;
          v[2]  = frcpr(d2 + SOFT);
          v[3]  = frcpr(d3 + SOFT);
          v[4]  = frcpr(d4 + SOFT);
          v[5]  = frcpr(d5 + SOFT);
          v[6]  = frcpr(d6 + SOFT);
          v[7]  = frcpr(d8 + SOFT);
          v[8]  = frcpr(d10 + SOFT);
          v[9]  = frcpr(d12 + SOFT);
          v[10] = frcpr(d14 + SOFT);
          v[11] = e;
          v[12] = e * r1;
          v[13] = FLOG(d + SOFT);
#pragma unroll
          for (int bb = 0; bb < 14; ++bb) {
            sF[bb] += v[bb];
            qF[bb] = fmaf(v[bb], v[bb], qF[bb]);
          }
        }
      }
      __syncthreads();
    }

    // Batched cross-rowgroup reduction: phase A (sums), phase B (sumsq).
    if (p < NPAIR) {
#pragma unroll
      for (int bb = 0; bb < 14; ++bb) sh.ds.red[rg][bb][p] = sF[bb];
    }
    __syncthreads();
    for (int i = tid; i < 14 * NPAIR; i += STHREADS) {
      int bb = i / NPAIR, pp = i - bb * NPAIR;
      float t2 = ((sh.ds.red[0][bb][pp] + sh.ds.red[1][bb][pp])
                 + sh.ds.red[2][bb][pp]) + sh.ds.red[3][bb][pp];
      psum[(size_t)b * NFEAT + 128 + bb * 120 + pp] = t2;
    }
    __syncthreads();
    if (p < NPAIR) {
#pragma unroll
      for (int bb = 0; bb < 14; ++bb) sh.ds.red[rg][bb][p] = qF[bb];
    }
    __syncthreads();
    for (int i = tid; i < 14 * NPAIR; i += STHREADS) {
      int bb = i / NPAIR, pp = i - bb * NPAIR;
      float t2 = ((sh.ds.red[0][bb][pp] + sh.ds.red[1][bb][pp])
                 + sh.ds.red[2][bb][pp]) + sh.ds.red[3][bb][pp];
      psumsq[(size_t)b * NFEAT + 128 + bb * 120 + pp] = t2;
    }
  }
}

// ---------------------------------------------------------------------------
// Pass 2a: stage-1 partial reduction (f32 in, f64 out). y==0 blocks also
// zero the atomic rank array. unroll-8 batches the strided L2 loads.
// ---------------------------------------------------------------------------
__global__ __launch_bounds__(256) void var1_kernel(const float* __restrict__ psum,
                                                   const float* __restrict__ psumsq,
                                                   double* __restrict__ psum2,
                                                   double* __restrict__ psumsq2,
                                                   int* __restrict__ rankA,
                                                   int slices) {
  int f = blockIdx.x * 256 + threadIdx.x;
  if (f >= NFEAT) return;
  if (blockIdx.y == 0) rankA[f] = 0;
  int b0 = blockIdx.y * slices;
  double s = 0.0, q = 0.0;
#pragma unroll 8
  for (int b = b0; b < b0 + slices; ++b) {
    s += (double)psum[(size_t)b * NFEAT + f];
    q += (double)psumsq[(size_t)b * NFEAT + f];
  }
  psum2[(size_t)blockIdx.y * NFEAT + f] = s;
  psumsq2[(size_t)blockIdx.y * NFEAT + f] = q;
}

// ---------------------------------------------------------------------------
// Pass 2b+3a merged: var + partial ranks via integer atomicAdd (order-exact).
// ---------------------------------------------------------------------------
__global__ __launch_bounds__(256) void var2rank1_kernel(const double* __restrict__ psum2,
                                                        const double* __restrict__ psumsq2,
                                                        int chunks,
                                                        int* __restrict__ rankA) {
  __shared__ double gvS[RGSZ];
  int tid = threadIdx.x;
  int g0 = blockIdx.y * RGSZ;
  const double N = (double)NB;
  if (tid < RGSZ) {
    double s = 0.0, q = 0.0;
#pragma unroll 8
    for (int b = 0; b < chunks; ++b) {
      s += psum2[(size_t)b * NFEAT + g0 + tid];
      q += psumsq2[(size_t)b * NFEAT + g0 + tid];
    }
    gvS[tid] = (q - s * s / N) / (N - 1.0);
  }
  __syncthreads();
  int f = blockIdx.x * 256 + tid;
  if (f >= NFEAT) return;
  double s = 0.0, q = 0.0;
#pragma unroll 8
  for (int b = 0; b < chunks; ++b) {
    s += psum2[(size_t)b * NFEAT + f];
    q += psumsq2[(size_t)b * NFEAT + f];
  }
  double vf = (q - s * s / N) / (N - 1.0);
  int cnt = 0;
#pragma unroll 11
  for (int k = 0; k < RGSZ; ++k) {
    double vg = gvS[k];
    int g = g0 + k;
    cnt += (int)((vg > vf) || (vg == vf && g < f));
  }
  atomicAdd(&rankA[f], cnt);
}

// ---------------------------------------------------------------------------
// Pass 4: resolve mask, build padded task list (merged 9-op set).
// Ordered slot assignment (ballot prefix). Emits per-slot a,b.
// ---------------------------------------------------------------------------
__global__ __launch_bounds__(1024) void rank2map_kernel(const int* __restrict__ rankA,
                                                        const int* __restrict__ mask,
                                                        const float* __restrict__ pmean,
                                                        const float* __restrict__ pstd,
                                                        int* __restrict__ taskW,
                                                        float* __restrict__ taskA,
                                                        float* __restrict__ taskB,
                                                        int* __restrict__ ntaskW) {
  __shared__ int topcolS[NPOLY];
  __shared__ int taskS[MAXT];
  __shared__ int cntS[32], pstartS[32];
  __shared__ int wcntS[8][32], wbaseS[8][32];
  __shared__ unsigned char IUs[NPAIR], JUs[NPAIR], IIs[28], JJs[28];
  int tid = threadIdx.x;
  init_tables_par(tid, IUs, JUs, IIs, JJs);
  for (int i = tid; i < MAXT; i += 1024) { taskS[i] = 31; taskA[i] = 0.0f; taskB[i] = 0.0f; }
  for (int f = tid; f < NFEAT; f += 1024) {
    int r = rankA[f];
    if (r < NPOLY) topcolS[r] = f;
  }
  __syncthreads();
  int pk = 31, op = 31;
  float aN = 0.0f, bN = 0.0f;
  int wave = tid >> 6, lane = tid & 63;
  unsigned long long mymask = 0;
  if (tid < NSEL) {   // waves 0..7, all lanes active
    int m = mask[tid];
    int c = topcolS[m];
    aN = frcp(pstd[m]);
    bN = -pmean[m] * aN;
    pk = pack_plan(c, IUs, JUs, IIs, JJs);
    op = pk & 31;
    for (int o = 0; o < 32; ++o) {
      unsigned long long bm = __ballot(op == o);
      if (lane == 0) wcntS[wave][o] = __popcll(bm);
      if (op == o) mymask = bm;
    }
  }
  __syncthreads();
  if (tid < 32) {
    int c = 0;
    for (int w2 = 0; w2 < 8; ++w2) { wbaseS[w2][tid] = c; c += wcntS[w2][tid]; }
    cntS[tid] = c;
  }
  __syncthreads();
  if (tid == 0) {
    int pcum = 0;
    for (int o = 0; o < 32; ++o) {
      pstartS[o] = pcum;
      pcum += (cntS[o] + 63) / 64 * 64;
    }
    ntaskW[0] = pcum;
  }
  __syncthreads();
  if (tid < NSEL) {
    int slot = pstartS[op] + wbaseS[wave][op]
             + (int)__popcll(mymask & ((1ull << lane) - 1ull));
    taskS[slot] = pk | (tid << 19);
    taskA[slot] = aN;
    taskB[slot] = bN;
  }
  __syncthreads();
  for (int i = tid; i < MAXT; i += 1024) taskW[i] = taskS[i];
}

// ---------------------------------------------------------------------------
// Pass 5: per RO-row batch, evaluate the padded task list (9-op merged set).
// Tasks are BATCH-INVARIANT: preloaded once into registers (<=TPT per
// thread; ntask 64-aligned => per-thread count wave-uniform; fully-unrolled
// static k indexing keeps them in VGPRs). op wave-uniform per (wave,k) ->
// readfirstlane scalar switch. Staged rowS store. rpb_out=32.
// ---------------------------------------------------------------------------
__global__ __launch_bounds__(256, 6) void out_kernel(const float* __restrict__ z,
                                                     const float* __restrict__ zmean,
                                                     const float* __restrict__ zstd,
                                                     const int* __restrict__ taskW,
                                                     const float* __restrict__ taskA,
                                                     const float* __restrict__ taskB,
                                                     const int* __restrict__ ntaskW,
                                                     float* __restrict__ out,
                                                     int rows_per_block) {
  __shared__ __align__(16) float zmS[ZD];
  __shared__ __align__(16) float rzS[ZD];
  __shared__ __align__(16) float znS[RO * ZD];
  __shared__ float zcS[RO * 32], dS[RO * NPAIR];
  __shared__ __align__(16) float rowS[RO * NSEL];
  __shared__ unsigned char IUs[NPAIR], JUs[NPAIR], IIs[28], JJs[28];
  int tid = threadIdx.x;
  int row0 = blockIdx.x * rows_per_block;
  int row1 = min(row0 + rows_per_block, NB);
  const float4* z4 = (const float4*)(z + (size_t)row0 * ZD);
  float4 cur = z4[tid];                       // prologue prefetch
  init_tables_par(tid, IUs, JUs, IIs, JJs);
  if (tid < ZD) { zmS[tid] = zmean[tid]; rzS[tid] = frcp(zstd[tid]); }
  int ntask = ntaskW[0];

  // preload this thread's tasks (batch-invariant) into registers
  int   pkR[TPT];
  float aR[TPT], bR[TPT];
#pragma unroll
  for (int k = 0; k < TPT; ++k) {
    int s2 = tid + k * 256;
    if (s2 < ntask) { pkR[k] = taskW[s2]; aR[k] = taskA[s2]; bR[k] = taskB[s2]; }
    else            { pkR[k] = 31; aR[k] = 0.0f; bR[k] = 0.0f; }
  }
  __syncthreads();

  int nbat = (row1 - row0) / RO;
  for (int t2 = 0; t2 < nbat; ++t2) {
    int r0 = row0 + t2 * RO;
    {
      float4 v = cur;
      int rr = tid >> 5, c4 = tid & 31;
      v.x = fminf(fmaxf(v.x, -1e6f), 1e6f);
      v.y = fminf(fmaxf(v.y, -1e6f), 1e6f);
      v.z = fminf(fmaxf(v.z, -1e6f), 1e6f);
      v.w = fminf(fmaxf(v.w, -1e6f), 1e6f);
      if ((c4 & 1) == 0) {
        int node = c4 >> 1;
        zcS[rr * 32 + node * 2 + 0] = v.x;
        zcS[rr * 32 + node * 2 + 1] = v.y;
      }
      float4 m4 = ((const float4*)zmS)[c4];
      float4 s4 = ((const float4*)rzS)[c4];
      float4 o;
      o.x = (v.x - m4.x) * s4.x;
      o.y = (v.y - m4.y) * s4.y;
      o.z = (v.z - m4.z) * s4.z;
      o.w = (v.w - m4.w) * s4.w;
      ((float4*)znS)[tid] = o;
    }
    if (t2 + 1 < nbat) cur = z4[(size_t)(t2 + 1) * (RO * ZD / 4) + tid];  // prefetch
    __syncthreads();
    for (int t = tid; t < RO * 128; t += 256) {
      int p = t & 127;
      if (p < NPAIR) {
        int rr = t >> 7;
        int i = IUs[p], j = JUs[p];
        float dx = zcS[rr * 32 + i * 2 + 0] - zcS[rr * 32 + j * 2 + 0];
        float dy = zcS[rr * 32 + i * 2 + 1] - zcS[rr * 32 + j * 2 + 1];
        dx = fmaf(-10.0f, rintf(dx * 0.1f), dx);
        dy = fmaf(-10.0f, rintf(dy * 0.1f), dy);
        dS[rr * NPAIR + p] = sqrtf(dx * dx + dy * dy) + 1e-6f;
      }
    }
    __syncthreads();
#define RLV(BODY) { _Pragma("unroll") for (int rr = 0; rr < RO; ++rr) { \
      const float* znR = znS + rr * ZD; const float* dR = dS + rr * NPAIR; \
      (void)znR; (void)dR; float v; BODY; \
      if (valid) rowS[rr * NSEL + dst] = fmaf(v, aA, bA); } } break;
#pragma unroll
    for (int k = 0; k < TPT; ++k) {
      if (tid + k * 256 < ntask) {            // wave-uniform (ntask 64-aligned)
        int pk = pkR[k];
        float aA = aR[k], bA = bR[k];
        int op = pk & 31;
        int a0 = (pk >> 5) & 127, a1 = (pk >> 12) & 127, dst = (pk >> 19) & 511;
        bool valid = (op != 31);
        int wop = __builtin_amdgcn_readfirstlane(op);  // wave-uniform (64-padded segments)
        switch (wop) {
          case 0:  RLV({ v = znR[a0]; })
          case 1:  RLV({ v = dR[a0]; })
          case 2:  RLV({ float d = dR[a0];
                         float d2 = d * d;
                         float d4 = d2 * d2;
                         float d8 = d4 * d4;
                         float acc = (a1 & 8) ? d8 : 1.0f;   /* exact: x*1.0 == x */
                         acc *= (a1 & 4) ? d4 : 1.0f;
                         acc *= (a1 & 2) ? d2 : 1.0f;
                         acc *= (a1 & 1) ? d  : 1.0f;
                         v = frcpr(acc + SOFT); })
          case 3:  RLV({ const float* src = a1 ? znR : dR;
                         float x = src[a0];
                         x = a1 ? fminf(fmaxf(x, -10.0f), 2.0f) : -x;
                         v = FEXP(x); })
          case 4:  RLV({ float d = dR[a0]; v = FEXP(-d) * frcpr(d + SOFT); })
          case 5:  RLV({ const float* src = a1 ? znR : dR;
                         float x = src[a0];
                         x = a1 ? fabsf(x) : x;
                         v = FLOG(x + SOFT); })
          case 6:  RLV({ float x = znR[a0];
                         float vs = FSIN(x);
                         float vc = FCOS(x);
                         v = a1 ? vc : vs; })
          case 7:  RLV({ const float* zr = znR + a0;
                         float x4 = zr[4]; float x5 = zr[5]; float x6 = zr[6]; float x7 = zr[7];
                         v = x4 * x4 + x5 * x5 + x6 * x6 + x7 * x7; })
          case 8:  RLV({ v = znR[a0] * znR[a1]; })
          default: break;
        }
      }
    }
#undef RLV
    __syncthreads();
    {
      float4* o4 = (float4*)(out + (size_t)r0 * NSEL);
      const float4* r4 = (const float4*)rowS;
      for (int t = tid; t < RO * NSEL / 4; t += 256) o4[t] = r4[t];
    }
    __syncthreads();
  }
}

// ---------------------------------------------------------------------------
extern "C" void kernel_launch(void* const* d_in, const int* in_sizes, int n_in,
                              void* d_out, int out_size, void* d_ws, size_t ws_size,
                              hipStream_t stream) {
  const float* z     = (const float*)d_in[0];
  const float* zmean = (const float*)d_in[1];
  const float* zstd  = (const float*)d_in[2];
  const float* pmean = (const float*)d_in[3];
  const float* pstd  = (const float*)d_in[4];
  const int*   mask  = (const int*)d_in[5];
  float* out = (float*)d_out;

  size_t tail = (size_t)VCHUNK * NFEAT * 16 + (size_t)NFEAT * 4
              + MAXT * 12 + 4096;
  int G = 512;
  while (G > 1 && (size_t)G * NFEAT * 8 + tail > ws_size) G >>= 1;
  int chunks = (G < VCHUNK) ? G : VCHUNK;
  int slices = G / chunks;

  char* w = (char*)d_ws;
  float*  psum    = (float*)w;                 w += (size_t)G * NFEAT * 4;
  float*  psumsq  = (float*)w;                 w += (size_t)G * NFEAT * 4;
  double* psum2   = (double*)w;                w += (size_t)VCHUNK * NFEAT * 8;
  double* psumsq2 = (double*)w;                w += (size_t)VCHUNK * NFEAT * 8;
  int*    rankA   = (int*)w;                   w += (size_t)NFEAT * 4;
  int*    taskW   = (int*)w;                   w += MAXT * 4;
  float*  taskA   = (float*)w;                 w += MAXT * 4;
  float*  taskB   = (float*)w;                 w += MAXT * 4;
  int*    ntaskW  = (int*)w;

  int rpb_stats = NB / G;
  stats_kernel<<<dim3(2 * G), dim3(STHREADS), 0, stream>>>(z, zmean, zstd, psum, psumsq,
                                                           rpb_stats);
  var1_kernel<<<dim3((NFEAT + 255) / 256, chunks), dim3(256), 0, stream>>>(psum, psumsq,
                                                                           psum2, psumsq2,
                                                                           rankA, slices);
  var2rank1_kernel<<<dim3((NFEAT + 255) / 256, RSLICE), dim3(256), 0, stream>>>(psum2, psumsq2,
                                                                                chunks, rankA);
  rank2map_kernel<<<dim3(1), dim3(1024), 0, stream>>>(rankA, mask, pmean, pstd,
                                                      taskW, taskA, taskB, ntaskW);
  const int rpb_out = 32;
  out_kernel<<<dim3(NB / rpb_out), dim3(256), 0, stream>>>(z, zmean, zstd, taskW, taskA, taskB,
                                                           ntaskW, out, rpb_out);
}

// Round 19
// 71.047 us; speedup vs baseline: 1.0440x; 1.0440x over previous
//
#include <hip/hip_runtime.h>
#include <cstdint>
#include <cstddef>

#define NFEAT 3872
#define NPAIR 120
#define NB    32768
#define ZD    128
#define NPOLY 1000
#define NSEL  512
#define SOFT  1e-3f

#define STHREADS 512   // stats block size
#define NZSLOT   1856  // wave-uniform zn slot count (64-aligned op segments, fused)
#define ZCHUNK   4     // slots tid + k*512
#define SB       64    // superbatch rows (whole block share staged at once)
#define RO       8     // rows per batch, out
#define VCHUNK   32    // var reduction stage-1 chunk count (8 starved var1; r10 -3.2us)
#define RSLICE   32    // rank stage-1 slices (NFEAT/RSLICE = 121)
#define RGSZ     121   // NFEAT / RSLICE
#define MAXT     1280  // max padded tasks (9 ops: 512 + 9*63 = 1079)

// ---------------------------------------------------------------------------
// Feature id layout (reference order):
//   [0,128) zn | [128,1808) 14 dist blocks x 120 pairs | [1808,1936) zn^2
//   [1936,2064) sin | [2064,2192) cos | [2192,2320) log|zn|+1e-3
//   [2320,2448) exp(clip) | [2448,2464) p_sq | [2464,2912) intra | [2912,3872) inter
// stats zn plan word: op(3b) | a0(7b)<<3 | a1(7b)<<10 | fid(12b)<<17 (4095=none)
// out task word: op(5b) | a0(7b)<<5 | a1(7b)<<12 | dst(9b)<<19
// OUT op set (merged, 9 real ops; r9-proven).
// Experiment ledger: r12 direct scatter +1.7us; r13 rpb_out=16 +0.9us;
// r15/r16 merged-role stats (race, then trans-pipe serialization);
// r18 task-register preload +3.1us (5x switch replication blew I-cache).
// This is the r17-proven structure (71.10us).
// ---------------------------------------------------------------------------

// Newton-refined reciprocal: used only in cold/one-time paths.
__device__ __forceinline__ float frcp(float x) {
  float r = __builtin_amdgcn_rcpf(x);
  float e = fmaf(-x, r, 1.0f);
  return fmaf(r, e, r);
}
// Raw HW reciprocal (~1e-6 rel err) for hot loops: below the f32
// block-accumulation noise floor (~1e-5) that already passes.
__device__ __forceinline__ float frcpr(float x) {
  return __builtin_amdgcn_rcpf(x);
}

#define FSIN(x) __sinf(x)
#define FCOS(x) __cosf(x)
#define FLOG(x) __logf(x)
#define FEXP(x) __expf(x)

// Parallel table init.
__device__ __forceinline__ void init_tables_par(int tid, unsigned char* IUs, unsigned char* JUs,
                                                unsigned char* IIs, unsigned char* JJs) {
  if (tid < NPAIR) {
    int i = 0, rem = tid;
    while (rem >= 15 - i) { rem -= 15 - i; ++i; }
    IUs[tid] = (unsigned char)i; JUs[tid] = (unsigned char)(i + 1 + rem);
  }
  if (tid < 28) {
    int i = 0, rem = tid;
    while (rem >= 7 - i) { rem -= 7 - i; ++i; }
    IIs[tid] = (unsigned char)i; JJs[tid] = (unsigned char)(i + 1 + rem);
  }
}

// Out-kernel plan packing with the merged 9-op set (r9-proven).
__device__ __forceinline__ int pack_plan(int f, const unsigned char* IUs, const unsigned char* JUs,
                                         const unsigned char* IIs, const unsigned char* JJs) {
  int op = 31, a0 = 0, a1 = 0;
  if (f < 128) { op = 0; a0 = f; }
  else if (f < 1808) {
    int t = f - 128; int b = t / 120; int p = t - b * 120; a0 = p;
    if (b == 0) op = 1;
    else if (b == 11) { op = 3; a1 = 0; }
    else if (b == 12) op = 4;
    else if (b == 13) { op = 5; a1 = 0; }
    else {
      // b in 1..10 -> exponent n: 1, then POWERS = 2,3,4,5,6,8,10,12,14
      const int P[10] = {1, 2, 3, 4, 5, 6, 8, 10, 12, 14};
      op = 2; a1 = P[b - 1];
    }
  }
  else if (f < 1936) { op = 8; a0 = f - 1808; a1 = a0; }   // zn^2 == zn*zn
  else if (f < 2064) { op = 6; a0 = f - 1936; a1 = 0; }    // sin
  else if (f < 2192) { op = 6; a0 = f - 2064; a1 = 1; }    // cos
  else if (f < 2320) { op = 5; a0 = f - 2192; a1 = 1; }    // log|zn|+1e-3
  else if (f < 2448) { op = 3; a0 = f - 2320; a1 = 1; }    // exp(clip(zn))
  else if (f < 2464) { op = 7; a0 = (f - 2448) * 8; }
  else if (f < 2912) { int t = f - 2464; int n = t / 28; int qq = t - n * 28;
                       op = 8; a0 = n * 8 + IIs[qq]; a1 = n * 8 + JJs[qq]; }
  else if (f < NFEAT) { int t = f - 2912; int p = t >> 3; int kk = t & 7;
                        op = 8; a0 = IUs[p] * 8 + kk; a1 = JUs[p] * 8 + kk; }
  return op | (a0 << 5) | (a1 << 12);
}

// ---------------------------------------------------------------------------
// Wave-uniform slot layout, stats zn role (unchanged from r6).
// ---------------------------------------------------------------------------
__device__ __forceinline__ int decode_zslot(int s, const unsigned char* IUs, const unsigned char* JUs,
                                            const unsigned char* IIs, const unsigned char* JJs) {
  int op = 0, a0 = 0, a1 = 0, fid = 4095;
  if (s < 128) { op = 1; a0 = s; fid = s; }
  else if (s < 256) { op = 2; a0 = s - 128; fid = 1936 + (s - 128); }
  else if (s < 384) { op = 3; a0 = s - 256; fid = 2192 + (s - 256); }
  else if (s < 448) {
    int q = s - 384;
    op = 4;
    a0 = (q < 16) ? q * 8 : 0;       // pad lanes compute garbage, never stored
    if (q < 16) fid = 2448 + q;
  } else if (s < 896) {
    int t = s - 448;
    int n = t / 28, qq = t - n * 28;
    op = 5; a0 = n * 8 + IIs[qq]; a1 = n * 8 + JJs[qq]; fid = 2464 + t;
  } else if (s < NZSLOT) {
    int t = s - 896;
    int p = t >> 3, kk = t & 7;
    op = 5; a0 = IUs[p] * 8 + kk; a1 = JUs[p] * 8 + kk; fid = 2912 + t;
  }
  return op | (a0 << 3) | (a1 << 10) | (fid << 17);
}

// ---------------------------------------------------------------------------
// Pass 1 (merged, parity-interleaved roles; even = zn, odd = dist).
// Superbatch: stage all 64 rows once; 2 barriers in the compute path.
// f32 accumulation + f32 partial stores (promoted to f64 in var1).
// Dist reduction tail batched: all 14 features per phase -> 4 barriers.
// ---------------------------------------------------------------------------
__global__ __launch_bounds__(STHREADS) void stats_kernel(const float* __restrict__ z,
                                                         const float* __restrict__ zmean,
                                                         const float* __restrict__ zstd,
                                                         float* __restrict__ psum,
                                                         float* __restrict__ psumsq,
                                                         int rows_per_block) {
  __shared__ __align__(16) union {
    struct { float zm[ZD]; float rz[ZD]; float zn[SB * ZD]; } zns;       // ~33 KB
    struct { float zc[SB * 32]; float red[4][14][NPAIR]; } ds;           // ~34.3 KB
  } sh;
  __shared__ unsigned char IUs[NPAIR], JUs[NPAIR], IIs[28], JJs[28];
  int tid = threadIdx.x;
  init_tables_par(tid, IUs, JUs, IIs, JJs);
  int bx = blockIdx.x;
  int b = bx >> 1;
  int row0 = b * rows_per_block;
  int row1 = min(row0 + rows_per_block, NB);

  if ((bx & 1) == 0) {
    // ---------------- zn role ----------------
    if (tid < ZD) { sh.zns.zm[tid] = zmean[tid]; sh.zns.rz[tid] = frcp(zstd[tid]); }
    __syncthreads();

    int plan[ZCHUNK];
#pragma unroll
    for (int k = 0; k < ZCHUNK; ++k)
      plan[k] = decode_zslot(tid + k * STHREADS, IUs, JUs, IIs, JJs);

    float s[ZCHUNK], q[ZCHUNK], s2 = 0.0f, q2 = 0.0f;
#pragma unroll
    for (int k = 0; k < ZCHUNK; ++k) { s[k] = 0.0f; q[k] = 0.0f; }

#define ROWLOOP _Pragma("unroll 8") for (int rr = 0; rr < SB; ++rr)
#define ACC  { sk += v; qk = fmaf(v, v, qk); }
#define ACC2 { sk2 += v2; qk2 = fmaf(v2, v2, qk2); }

    for (int r0 = row0; r0 < row1; r0 += SB) {
      const float4* z4 = (const float4*)(z + (size_t)r0 * ZD);
#pragma unroll
      for (int u = 0; u < SB * ZD / 4 / STHREADS; ++u) {
        int t = u * STHREADS + tid;
        float4 v = z4[t];
        int c4 = t & 31;
        v.x = fminf(fmaxf(v.x, -1e6f), 1e6f);
        v.y = fminf(fmaxf(v.y, -1e6f), 1e6f);
        v.z = fminf(fmaxf(v.z, -1e6f), 1e6f);
        v.w = fminf(fmaxf(v.w, -1e6f), 1e6f);
        float4 m4 = ((const float4*)sh.zns.zm)[c4];
        float4 r4 = ((const float4*)sh.zns.rz)[c4];
        float4 o;
        o.x = (v.x - m4.x) * r4.x;
        o.y = (v.y - m4.y) * r4.y;
        o.z = (v.z - m4.z) * r4.z;
        o.w = (v.w - m4.w) * r4.w;
        ((float4*)sh.zns.zn)[t] = o;
      }
      __syncthreads();
      const float* znS = sh.zns.zn;
      // ---- chunk 0: mixed ops, wave-uniform switch ----
      {
        int pk = plan[0];
        int a0 = (pk >> 3) & 127, a1 = (pk >> 10) & 127;
        int wop = __builtin_amdgcn_readfirstlane(pk & 7);
        float sk = 0.0f, qk = 0.0f, sk2 = 0.0f, qk2 = 0.0f;
        switch (wop) {
          case 1: ROWLOOP { float v = znS[rr * ZD + a0];
                            float v2 = v * v; ACC ACC2 } break;
          case 2: ROWLOOP { float x = znS[rr * ZD + a0];
                            float v, v2; __sincosf(x, &v, &v2); ACC ACC2 } break;
          case 3: ROWLOOP { float x = znS[rr * ZD + a0];
                            float v = FLOG(fabsf(x) + 0.001f);
                            float xc = fminf(fmaxf(x, -10.0f), 2.0f);
                            float v2 = FEXP(xc); ACC ACC2 } break;
          case 4: ROWLOOP { const float* zr = znS + rr * ZD + a0;
                            float x4 = zr[4]; float x5 = zr[5]; float x6 = zr[6]; float x7 = zr[7];
                            float v = x4 * x4 + x5 * x5 + x6 * x6 + x7 * x7; ACC } break;
          case 5: ROWLOOP { const float* zr = znS + rr * ZD; float v = zr[a0] * zr[a1]; ACC } break;
          default: break;
        }
        s[0] += sk; q[0] += qk;
        if (wop >= 1 && wop <= 3) { s2 += sk2; q2 += qk2; }
      }
      // ---- chunks 1..3: statically all-op5 (chunk 3 idle past 1856) ----
#pragma unroll
      for (int k = 1; k < ZCHUNK; ++k) {
        int pk = plan[k];
        int a0 = (pk >> 3) & 127, a1 = (pk >> 10) & 127;
        int act = __builtin_amdgcn_readfirstlane((int)(((pk >> 17) & 4095) != 4095));
        if (act) {
          float sk = 0.0f, qk = 0.0f;
          ROWLOOP { const float* zr = znS + rr * ZD; float v = zr[a0] * zr[a1]; ACC }
          s[k] += sk; q[k] += qk;
        }
      }
      __syncthreads();
    }
#undef ROWLOOP
#undef ACC
#undef ACC2

#pragma unroll
    for (int k = 0; k < ZCHUNK; ++k) {
      int fid = (plan[k] >> 17) & 4095;
      int opk = plan[k] & 7;
      if (fid != 4095) {
        psum[(size_t)b * NFEAT + fid] = s[k];
        psumsq[(size_t)b * NFEAT + fid] = q[k];
        if (k == 0 && opk >= 1 && opk <= 3) {
          int fid2 = fid + ((opk == 1) ? 1808 : 128);
          psum[(size_t)b * NFEAT + fid2] = s2;
          psumsq[(size_t)b * NFEAT + fid2] = q2;
        }
      }
    }
  } else {
    // ---------------- dist role ----------------
    __syncthreads();    // tables visible
    int p  = tid & 127;
    int rg = tid >> 7;                         // 0..3
    int ni = (p < NPAIR) ? IUs[p] : 0;
    int nj = (p < NPAIR) ? JUs[p] : 0;

    float sF[14], qF[14];
#pragma unroll
    for (int bb = 0; bb < 14; ++bb) { sF[bb] = 0.0f; qF[bb] = 0.0f; }

    for (int r0 = row0; r0 < row1; r0 += SB) {
#pragma unroll
      for (int u = 0; u < SB * 32 / STHREADS; ++u) {
        int t = u * STHREADS + tid;
        int rr = t >> 5, c = t & 31;
        int col = ((c >> 1) << 3) + (c & 1);
        float v = z[(size_t)(r0 + rr) * ZD + col];
        sh.ds.zc[t] = fminf(fmaxf(v, -1e6f), 1e6f);
      }
      __syncthreads();
      if (p < NPAIR) {
        for (int rr = rg; rr < SB; rr += 4) {
          const float* zc = sh.ds.zc + rr * 32;
          float dx = zc[ni * 2 + 0] - zc[nj * 2 + 0];
          float dy = zc[ni * 2 + 1] - zc[nj * 2 + 1];
          dx = fmaf(-10.0f, rintf(dx * 0.1f), dx);
          dy = fmaf(-10.0f, rintf(dy * 0.1f), dy);
          float d = sqrtf(dx * dx + dy * dy) + 1e-6f;
          float e = FEXP(-d);
          float d2 = d * d,   d3 = d2 * d,  d4 = d2 * d2, d5 = d4 * d, d6 = d4 * d2;
          float d8 = d4 * d4, d10 = d8 * d2, d12 = d8 * d4, d14 = d12 * d2;
          float r1 = frcpr(d + SOFT);
          float v[14];
          v[0]  = d;
          v[1]  = r1;
          v[2]  = frcpr(d2 + SOFT);
          v[3]  = frcpr(d3 + SOFT);
          v[4]  = frcpr(d4 + SOFT);
          v[5]  = frcpr(d5 + SOFT);
          v[6]  = frcpr(d6 + SOFT);
          v[7]  = frcpr(d8 + SOFT);
          v[8]  = frcpr(d10 + SOFT);
          v[9]  = frcpr(d12 + SOFT);
          v[10] = frcpr(d14 + SOFT);
          v[11] = e;
          v[12] = e * r1;
          v[13] = FLOG(d + SOFT);
#pragma unroll
          for (int bb = 0; bb < 14; ++bb) {
            sF[bb] += v[bb];
            qF[bb] = fmaf(v[bb], v[bb], qF[bb]);
          }
        }
      }
      __syncthreads();
    }

    // Batched cross-rowgroup reduction: phase A (sums), phase B (sumsq).
    if (p < NPAIR) {
#pragma unroll
      for (int bb = 0; bb < 14; ++bb) sh.ds.red[rg][bb][p] = sF[bb];
    }
    __syncthreads();
    for (int i = tid; i < 14 * NPAIR; i += STHREADS) {
      int bb = i / NPAIR, pp = i - bb * NPAIR;
      float t2 = ((sh.ds.red[0][bb][pp] + sh.ds.red[1][bb][pp])
                 + sh.ds.red[2][bb][pp]) + sh.ds.red[3][bb][pp];
      psum[(size_t)b * NFEAT + 128 + bb * 120 + pp] = t2;
    }
    __syncthreads();
    if (p < NPAIR) {
#pragma unroll
      for (int bb = 0; bb < 14; ++bb) sh.ds.red[rg][bb][p] = qF[bb];
    }
    __syncthreads();
    for (int i = tid; i < 14 * NPAIR; i += STHREADS) {
      int bb = i / NPAIR, pp = i - bb * NPAIR;
      float t2 = ((sh.ds.red[0][bb][pp] + sh.ds.red[1][bb][pp])
                 + sh.ds.red[2][bb][pp]) + sh.ds.red[3][bb][pp];
      psumsq[(size_t)b * NFEAT + 128 + bb * 120 + pp] = t2;
    }
  }
}

// ---------------------------------------------------------------------------
// Pass 2a: stage-1 partial reduction (f32 in, f64 out). y==0 blocks also
// zero the atomic rank array. unroll-8 batches the strided L2 loads.
// ---------------------------------------------------------------------------
__global__ __launch_bounds__(256) void var1_kernel(const float* __restrict__ psum,
                                                   const float* __restrict__ psumsq,
                                                   double* __restrict__ psum2,
                                                   double* __restrict__ psumsq2,
                                                   int* __restrict__ rankA,
                                                   int slices) {
  int f = blockIdx.x * 256 + threadIdx.x;
  if (f >= NFEAT) return;
  if (blockIdx.y == 0) rankA[f] = 0;
  int b0 = blockIdx.y * slices;
  double s = 0.0, q = 0.0;
#pragma unroll 8
  for (int b = b0; b < b0 + slices; ++b) {
    s += (double)psum[(size_t)b * NFEAT + f];
    q += (double)psumsq[(size_t)b * NFEAT + f];
  }
  psum2[(size_t)blockIdx.y * NFEAT + f] = s;
  psumsq2[(size_t)blockIdx.y * NFEAT + f] = q;
}

// ---------------------------------------------------------------------------
// Pass 2b+3a merged: var + partial ranks via integer atomicAdd (order-exact).
// ---------------------------------------------------------------------------
__global__ __launch_bounds__(256) void var2rank1_kernel(const double* __restrict__ psum2,
                                                        const double* __restrict__ psumsq2,
                                                        int chunks,
                                                        int* __restrict__ rankA) {
  __shared__ double gvS[RGSZ];
  int tid = threadIdx.x;
  int g0 = blockIdx.y * RGSZ;
  const double N = (double)NB;
  if (tid < RGSZ) {
    double s = 0.0, q = 0.0;
#pragma unroll 8
    for (int b = 0; b < chunks; ++b) {
      s += psum2[(size_t)b * NFEAT + g0 + tid];
      q += psumsq2[(size_t)b * NFEAT + g0 + tid];
    }
    gvS[tid] = (q - s * s / N) / (N - 1.0);
  }
  __syncthreads();
  int f = blockIdx.x * 256 + tid;
  if (f >= NFEAT) return;
  double s = 0.0, q = 0.0;
#pragma unroll 8
  for (int b = 0; b < chunks; ++b) {
    s += psum2[(size_t)b * NFEAT + f];
    q += psumsq2[(size_t)b * NFEAT + f];
  }
  double vf = (q - s * s / N) / (N - 1.0);
  int cnt = 0;
#pragma unroll 11
  for (int k = 0; k < RGSZ; ++k) {
    double vg = gvS[k];
    int g = g0 + k;
    cnt += (int)((vg > vf) || (vg == vf && g < f));
  }
  atomicAdd(&rankA[f], cnt);
}

// ---------------------------------------------------------------------------
// Pass 4: resolve mask, build padded task list (merged 9-op set).
// Ordered slot assignment (ballot prefix). Emits per-slot a,b.
// ---------------------------------------------------------------------------
__global__ __launch_bounds__(1024) void rank2map_kernel(const int* __restrict__ rankA,
                                                        const int* __restrict__ mask,
                                                        const float* __restrict__ pmean,
                                                        const float* __restrict__ pstd,
                                                        int* __restrict__ taskW,
                                                        float* __restrict__ taskA,
                                                        float* __restrict__ taskB,
                                                        int* __restrict__ ntaskW) {
  __shared__ int topcolS[NPOLY];
  __shared__ int taskS[MAXT];
  __shared__ int cntS[32], pstartS[32];
  __shared__ int wcntS[8][32], wbaseS[8][32];
  __shared__ unsigned char IUs[NPAIR], JUs[NPAIR], IIs[28], JJs[28];
  int tid = threadIdx.x;
  init_tables_par(tid, IUs, JUs, IIs, JJs);
  for (int i = tid; i < MAXT; i += 1024) { taskS[i] = 31; taskA[i] = 0.0f; taskB[i] = 0.0f; }
  for (int f = tid; f < NFEAT; f += 1024) {
    int r = rankA[f];
    if (r < NPOLY) topcolS[r] = f;
  }
  __syncthreads();
  int pk = 31, op = 31;
  float aN = 0.0f, bN = 0.0f;
  int wave = tid >> 6, lane = tid & 63;
  unsigned long long mymask = 0;
  if (tid < NSEL) {   // waves 0..7, all lanes active
    int m = mask[tid];
    int c = topcolS[m];
    aN = frcp(pstd[m]);
    bN = -pmean[m] * aN;
    pk = pack_plan(c, IUs, JUs, IIs, JJs);
    op = pk & 31;
    for (int o = 0; o < 32; ++o) {
      unsigned long long bm = __ballot(op == o);
      if (lane == 0) wcntS[wave][o] = __popcll(bm);
      if (op == o) mymask = bm;
    }
  }
  __syncthreads();
  if (tid < 32) {
    int c = 0;
    for (int w2 = 0; w2 < 8; ++w2) { wbaseS[w2][tid] = c; c += wcntS[w2][tid]; }
    cntS[tid] = c;
  }
  __syncthreads();
  if (tid == 0) {
    int pcum = 0;
    for (int o = 0; o < 32; ++o) {
      pstartS[o] = pcum;
      pcum += (cntS[o] + 63) / 64 * 64;
    }
    ntaskW[0] = pcum;
  }
  __syncthreads();
  if (tid < NSEL) {
    int slot = pstartS[op] + wbaseS[wave][op]
             + (int)__popcll(mymask & ((1ull << lane) - 1ull));
    taskS[slot] = pk | (tid << 19);
    taskA[slot] = aN;
    taskB[slot] = bN;
  }
  __syncthreads();
  for (int i = tid; i < MAXT; i += 1024) taskW[i] = taskS[i];
}

// ---------------------------------------------------------------------------
// Pass 5: per RO-row batch, evaluate padded task list (9-op merged set).
// op wave-uniform (64-padded segments) -> readfirstlane scalar switch.
// Task triple software-pipelined. Staged rowS store. rpb_out=32 (r11).
// ---------------------------------------------------------------------------
__global__ __launch_bounds__(256, 6) void out_kernel(const float* __restrict__ z,
                                                     const float* __restrict__ zmean,
                                                     const float* __restrict__ zstd,
                                                     const int* __restrict__ taskW,
                                                     const float* __restrict__ taskA,
                                                     const float* __restrict__ taskB,
                                                     const int* __restrict__ ntaskW,
                                                     float* __restrict__ out,
                                                     int rows_per_block) {
  __shared__ __align__(16) float zmS[ZD];
  __shared__ __align__(16) float rzS[ZD];
  __shared__ __align__(16) float znS[RO * ZD];
  __shared__ float zcS[RO * 32], dS[RO * NPAIR];
  __shared__ __align__(16) float rowS[RO * NSEL];
  __shared__ unsigned char IUs[NPAIR], JUs[NPAIR], IIs[28], JJs[28];
  int tid = threadIdx.x;
  int row0 = blockIdx.x * rows_per_block;
  int row1 = min(row0 + rows_per_block, NB);
  const float4* z4 = (const float4*)(z + (size_t)row0 * ZD);
  float4 cur = z4[tid];                       // prologue prefetch
  init_tables_par(tid, IUs, JUs, IIs, JJs);
  if (tid < ZD) { zmS[tid] = zmean[tid]; rzS[tid] = frcp(zstd[tid]); }
  int ntask = ntaskW[0];
  __syncthreads();

  int nbat = (row1 - row0) / RO;
  for (int t2 = 0; t2 < nbat; ++t2) {
    int r0 = row0 + t2 * RO;
    {
      float4 v = cur;
      int rr = tid >> 5, c4 = tid & 31;
      v.x = fminf(fmaxf(v.x, -1e6f), 1e6f);
      v.y = fminf(fmaxf(v.y, -1e6f), 1e6f);
      v.z = fminf(fmaxf(v.z, -1e6f), 1e6f);
      v.w = fminf(fmaxf(v.w, -1e6f), 1e6f);
      if ((c4 & 1) == 0) {
        int node = c4 >> 1;
        zcS[rr * 32 + node * 2 + 0] = v.x;
        zcS[rr * 32 + node * 2 + 1] = v.y;
      }
      float4 m4 = ((const float4*)zmS)[c4];
      float4 s4 = ((const float4*)rzS)[c4];
      float4 o;
      o.x = (v.x - m4.x) * s4.x;
      o.y = (v.y - m4.y) * s4.y;
      o.z = (v.z - m4.z) * s4.z;
      o.w = (v.w - m4.w) * s4.w;
      ((float4*)znS)[tid] = o;
    }
    if (t2 + 1 < nbat) cur = z4[(size_t)(t2 + 1) * (RO * ZD / 4) + tid];  // prefetch
    __syncthreads();
    for (int t = tid; t < RO * 128; t += 256) {
      int p = t & 127;
      if (p < NPAIR) {
        int rr = t >> 7;
        int i = IUs[p], j = JUs[p];
        float dx = zcS[rr * 32 + i * 2 + 0] - zcS[rr * 32 + j * 2 + 0];
        float dy = zcS[rr * 32 + i * 2 + 1] - zcS[rr * 32 + j * 2 + 1];
        dx = fmaf(-10.0f, rintf(dx * 0.1f), dx);
        dy = fmaf(-10.0f, rintf(dy * 0.1f), dy);
        dS[rr * NPAIR + p] = sqrtf(dx * dx + dy * dy) + 1e-6f;
      }
    }
    __syncthreads();
#define RLV(BODY) { _Pragma("unroll") for (int rr = 0; rr < RO; ++rr) { \
      const float* znR = znS + rr * ZD; const float* dR = dS + rr * NPAIR; \
      (void)znR; (void)dR; float v; BODY; \
      if (valid) rowS[rr * NSEL + dst] = fmaf(v, aA, bA); } } break;
    {
      int s2 = tid;
      int pk = 31; float aA = 0.0f, bA = 0.0f;
      if (s2 < ntask) { pk = taskW[s2]; aA = taskA[s2]; bA = taskB[s2]; }
      for (; s2 < ntask; s2 += 256) {
        // software-pipeline: issue next task triple before the body
        int s2n = s2 + 256;
        int pk_n = 31; float aA_n = 0.0f, bA_n = 0.0f;
        if (s2n < ntask) { pk_n = taskW[s2n]; aA_n = taskA[s2n]; bA_n = taskB[s2n]; }
        int op = pk & 31;
        int a0 = (pk >> 5) & 127, a1 = (pk >> 12) & 127, dst = (pk >> 19) & 511;
        bool valid = (op != 31);
        int wop = __builtin_amdgcn_readfirstlane(op);  // wave-uniform (64-padded segments)
        switch (wop) {
          case 0:  RLV({ v = znR[a0]; })
          case 1:  RLV({ v = dR[a0]; })
          case 2:  RLV({ float d = dR[a0];
                         float d2 = d * d;
                         float d4 = d2 * d2;
                         float d8 = d4 * d4;
                         float acc = (a1 & 8) ? d8 : 1.0f;   /* exact: x*1.0 == x */
                         acc *= (a1 & 4) ? d4 : 1.0f;
                         acc *= (a1 & 2) ? d2 : 1.0f;
                         acc *= (a1 & 1) ? d  : 1.0f;
                         v = frcpr(acc + SOFT); })
          case 3:  RLV({ const float* src = a1 ? znR : dR;
                         float x = src[a0];
                         x = a1 ? fminf(fmaxf(x, -10.0f), 2.0f) : -x;
                         v = FEXP(x); })
          case 4:  RLV({ float d = dR[a0]; v = FEXP(-d) * frcpr(d + SOFT); })
          case 5:  RLV({ const float* src = a1 ? znR : dR;
                         float x = src[a0];
                         x = a1 ? fabsf(x) : x;
                         v = FLOG(x + SOFT); })
          case 6:  RLV({ float x = znR[a0];
                         float vs = FSIN(x);
                         float vc = FCOS(x);
                         v = a1 ? vc : vs; })
          case 7:  RLV({ const float* zr = znR + a0;
                         float x4 = zr[4]; float x5 = zr[5]; float x6 = zr[6]; float x7 = zr[7];
                         v = x4 * x4 + x5 * x5 + x6 * x6 + x7 * x7; })
          case 8:  RLV({ v = znR[a0] * znR[a1]; })
          default: break;
        }
        pk = pk_n; aA = aA_n; bA = bA_n;
      }
    }
#undef RLV
    __syncthreads();
    {
      float4* o4 = (float4*)(out + (size_t)r0 * NSEL);
      const float4* r4 = (const float4*)rowS;
      for (int t = tid; t < RO * NSEL / 4; t += 256) o4[t] = r4[t];
    }
    __syncthreads();
  }
}

// ---------------------------------------------------------------------------
extern "C" void kernel_launch(void* const* d_in, const int* in_sizes, int n_in,
                              void* d_out, int out_size, void* d_ws, size_t ws_size,
                              hipStream_t stream) {
  const float* z     = (const float*)d_in[0];
  const float* zmean = (const float*)d_in[1];
  const float* zstd  = (const float*)d_in[2];
  const float* pmean = (const float*)d_in[3];
  const float* pstd  = (const float*)d_in[4];
  const int*   mask  = (const int*)d_in[5];
  float* out = (float*)d_out;

  size_t tail = (size_t)VCHUNK * NFEAT * 16 + (size_t)NFEAT * 4
              + MAXT * 12 + 4096;
  int G = 512;
  while (G > 1 && (size_t)G * NFEAT * 8 + tail > ws_size) G >>= 1;
  int chunks = (G < VCHUNK) ? G : VCHUNK;
  int slices = G / chunks;

  char* w = (char*)d_ws;
  float*  psum    = (float*)w;                 w += (size_t)G * NFEAT * 4;
  float*  psumsq  = (float*)w;                 w += (size_t)G * NFEAT * 4;
  double* psum2   = (double*)w;                w += (size_t)VCHUNK * NFEAT * 8;
  double* psumsq2 = (double*)w;                w += (size_t)VCHUNK * NFEAT * 8;
  int*    rankA   = (int*)w;                   w += (size_t)NFEAT * 4;
  int*    taskW   = (int*)w;                   w += MAXT * 4;
  float*  taskA   = (float*)w;                 w += MAXT * 4;
  float*  taskB   = (float*)w;                 w += MAXT * 4;
  int*    ntaskW  = (int*)w;

  int rpb_stats = NB / G;
  stats_kernel<<<dim3(2 * G), dim3(STHREADS), 0, stream>>>(z, zmean, zstd, psum, psumsq,
                                                           rpb_stats);
  var1_kernel<<<dim3((NFEAT + 255) / 256, chunks), dim3(256), 0, stream>>>(psum, psumsq,
                                                                           psum2, psumsq2,
                                                                           rankA, slices);
  var2rank1_kernel<<<dim3((NFEAT + 255) / 256, RSLICE), dim3(256), 0, stream>>>(psum2, psumsq2,
                                                                                chunks, rankA);
  rank2map_kernel<<<dim3(1), dim3(1024), 0, stream>>>(rankA, mask, pmean, pstd,
                                                      taskW, taskA, taskB, ntaskW);
  const int rpb_out = 32;
  out_kernel<<<dim3(NB / rpb_out), dim3(256), 0, stream>>>(z, zmean, zstd, taskW, taskA, taskB,
                                                           ntaskW, out, rpb_out);
}